// Round 1
// baseline (121.926 us; speedup 1.0000x reference)
//
#include <hip/hip_runtime.h>

#define B_ 4
#define C_ 128
#define N_ 4096

typedef __bf16 bf16x8 __attribute__((ext_vector_type(8)));
typedef float  f32x16 __attribute__((ext_vector_type(16)));
typedef int    i32x4  __attribute__((ext_vector_type(4)));
typedef int    i32x2  __attribute__((ext_vector_type(2)));

static __device__ __forceinline__ unsigned int bfbits(float f) {
    unsigned int u = __float_as_uint(f);
    u += 0x7FFFu + ((u >> 16) & 1u);   // round-to-nearest-even
    return u >> 16;
}
static __device__ __forceinline__ int pk2(float lo, float hi) {
    return (int)(bfbits(lo) | (bfbits(hi) << 16));
}

// ---------------- projection: q/k/v = W @ x + b (1x1 conv) -------------
// qT,kT stored [B][N][C] bf16 (transposed); v stored [B][C][N] bf16.
__global__ __launch_bounds__(256) void proj_kernel(
    const float* __restrict__ x,
    const float* __restrict__ Wq, const float* __restrict__ bq,
    const float* __restrict__ Wk, const float* __restrict__ bk,
    const float* __restrict__ Wv, const float* __restrict__ bv,
    unsigned short* __restrict__ qT, unsigned short* __restrict__ kTt,
    unsigned short* __restrict__ vMat)
{
    const int tid  = threadIdx.x;
    const int wave = tid >> 6;
    const int lane = tid & 63;
    const int col  = lane & 31;
    const int h    = lane >> 5;

    const int jw  = blockIdx.x * 4 + wave;   // 0..1535 = mat*512 + b*128 + nb
    const int mat = jw >> 9;
    const int rem = jw & 511;
    const int b   = rem >> 7;
    const int nb  = rem & 127;
    const int n   = nb * 32 + col;

    const float* W    = (mat == 0) ? Wq : (mat == 1) ? Wk : Wv;
    const float* bias = (mat == 0) ? bq : (mat == 1) ? bk : bv;

    // B-operand fragments of x: element e of group h <-> c = ch*16 + 8h + e
    bf16x8 xf[8];
    const float* xcol = x + (size_t)b * C_ * N_ + n;
    #pragma unroll
    for (int ch = 0; ch < 8; ++ch) {
        const int c0 = ch * 16 + 8 * h;
        i32x4 r;
        r[0] = pk2(xcol[(size_t)(c0 + 0) * N_], xcol[(size_t)(c0 + 1) * N_]);
        r[1] = pk2(xcol[(size_t)(c0 + 2) * N_], xcol[(size_t)(c0 + 3) * N_]);
        r[2] = pk2(xcol[(size_t)(c0 + 4) * N_], xcol[(size_t)(c0 + 5) * N_]);
        r[3] = pk2(xcol[(size_t)(c0 + 6) * N_], xcol[(size_t)(c0 + 7) * N_]);
        xf[ch] = __builtin_bit_cast(bf16x8, r);
    }

    f32x16 acc[4];
    #pragma unroll
    for (int ob = 0; ob < 4; ++ob)
        #pragma unroll
        for (int rr = 0; rr < 16; ++rr) acc[ob][rr] = 0.0f;

    #pragma unroll
    for (int ch = 0; ch < 8; ++ch) {
        #pragma unroll
        for (int ob = 0; ob < 4; ++ob) {
            const int o = ob * 32 + col;
            const float* wr = W + (size_t)o * C_ + ch * 16 + 8 * h;
            i32x4 wiv;
            wiv[0] = pk2(wr[0], wr[1]);
            wiv[1] = pk2(wr[2], wr[3]);
            wiv[2] = pk2(wr[4], wr[5]);
            wiv[3] = pk2(wr[6], wr[7]);
            acc[ob] = __builtin_amdgcn_mfma_f32_32x32x16_bf16(
                __builtin_bit_cast(bf16x8, wiv), xf[ch], acc[ob], 0, 0, 0);
        }
    }

    // D[o][n]: lane col n = l&31, row o = ob*32 + (rr&3) + 8*(rr>>2) + 4h
    if (mat < 2) {
        unsigned short* dst = ((mat == 0) ? qT : kTt) + (size_t)(b * N_ + n) * C_;
        #pragma unroll
        for (int ob = 0; ob < 4; ++ob) {
            #pragma unroll
            for (int qd = 0; qd < 4; ++qd) {
                const int obase = ob * 32 + 8 * qd + 4 * h;
                const float f0 = acc[ob][4 * qd + 0] + bias[obase + 0];
                const float f1 = acc[ob][4 * qd + 1] + bias[obase + 1];
                const float f2 = acc[ob][4 * qd + 2] + bias[obase + 2];
                const float f3 = acc[ob][4 * qd + 3] + bias[obase + 3];
                i32x2 st; st[0] = pk2(f0, f1); st[1] = pk2(f2, f3);
                *(i32x2*)(dst + obase) = st;
            }
        }
    } else {
        unsigned short* dst = vMat + (size_t)b * C_ * N_ + n;
        #pragma unroll
        for (int ob = 0; ob < 4; ++ob) {
            #pragma unroll
            for (int rr = 0; rr < 16; ++rr) {
                const int o = ob * 32 + (rr & 3) + 8 * (rr >> 2) + 4 * h;
                dst[(size_t)o * N_] = (unsigned short)bfbits(acc[ob][rr] + bias[o]);
            }
        }
    }
}

// ---------------- flash attention + residual ---------------------------
// 256 WGs x 512 thr. 8 waves = 2 q-blocks(32) x 4 key-splits(1024 keys).
__global__ __launch_bounds__(512, 2) void attn_kernel(
    const float* __restrict__ x,
    const unsigned short* __restrict__ qT,
    const unsigned short* __restrict__ kTt,
    const unsigned short* __restrict__ vMat,
    float* __restrict__ out)
{
    __shared__ __align__(16) char smem[65536];

    const int tid  = threadIdx.x;
    const int wave = tid >> 6;
    const int lane = tid & 63;
    const int l31  = lane & 31;
    const int h    = lane >> 5;
    const int s    = wave >> 1;        // key split 0..3
    const int qb   = wave & 1;         // q block within WG

    const int Wg = blockIdx.x;
    const int b  = (Wg & 7) >> 1;                  // XCD-friendly mapping
    const int qg = (Wg >> 3) * 2 + (Wg & 1);       // 0..63
    const int i0 = qg * 64 + qb * 32;

    char* kbuf = smem + s * 16384;
    char* vbuf = kbuf + 8192;

    // Q fragments (held for whole kernel): element e <-> c = ch*16 + 8h + e
    bf16x8 qf[8];
    {
        const unsigned short* qrow = qT + (size_t)(b * N_ + i0 + l31) * C_;
        #pragma unroll
        for (int ch = 0; ch < 8; ++ch)
            qf[ch] = __builtin_bit_cast(bf16x8, *(const i32x4*)(qrow + ch * 16 + 8 * h));
    }

    f32x16 accO[4];
    #pragma unroll
    for (int cb = 0; cb < 4; ++cb)
        #pragma unroll
        for (int rr = 0; rr < 16; ++rr) accO[cb][rr] = 0.0f;
    float m_run = -1e30f, l_run = 0.0f;

    // staging roles: 128 threads per split stage kT(8KB)+v(8KB) per tile
    const int ts  = tid & 127;
    const int jr  = ts >> 2;
    const int seg = ts & 3;
    const int j0  = s * 1024;
    const char* kg = (const char*)kTt + (size_t)(b * N_) * C_ * 2;
    const char* vg = (const char*)vMat + (size_t)(b * C_ + ts) * N_ * 2;

    i32x4 kst[4], vst[4];
    #pragma unroll
    for (int u = 0; u < 4; ++u) {
        kst[u] = *(const i32x4*)(kg + (size_t)(j0 + jr) * 256 + seg * 64 + u * 16);
        vst[u] = *(const i32x4*)(vg + (size_t)j0 * 2 + u * 16);
    }

    auto write_tile = [&]() {
        #pragma unroll
        for (int u = 0; u < 4; ++u) {
            *(i32x4*)(kbuf + jr * 256 + ((seg * 64 + u * 16) ^ ((jr & 7) << 4))) = kst[u];
            i32x2 lo; lo[0] = vst[u][0]; lo[1] = vst[u][1];
            i32x2 hi; hi[0] = vst[u][2]; hi[1] = vst[u][3];
            *(i32x2*)(vbuf + ts * 64 + ((u * 16)     ^ ((ts & 7) << 3))) = lo;
            *(i32x2*)(vbuf + ts * 64 + ((u * 16 + 8) ^ ((ts & 7) << 3))) = hi;
        }
    };
    write_tile();

    #pragma unroll 1
    for (int t = 0; t < 32; ++t) {
        __syncthreads();                       // LDS tile t visible
        if (t + 1 < 32) {                      // prefetch next tile into regs
            const int jn = j0 + (t + 1) * 32;
            #pragma unroll
            for (int u = 0; u < 4; ++u) {
                kst[u] = *(const i32x4*)(kg + (size_t)(jn + jr) * 256 + seg * 64 + u * 16);
                vst[u] = *(const i32x4*)(vg + (size_t)jn * 2 + u * 16);
            }
        }

        // E^T[j][i] = sum_c K[c,j] Q[c,i] : A=K^T frag (row j=l31), B=Q frag
        f32x16 e;
        #pragma unroll
        for (int rr = 0; rr < 16; ++rr) e[rr] = 0.0f;
        {
            const char* krow = kbuf + l31 * 256;
            const int   swz  = (l31 & 7) << 4;
            #pragma unroll
            for (int ch = 0; ch < 8; ++ch) {
                bf16x8 kf = __builtin_bit_cast(bf16x8,
                    *(const i32x4*)(krow + ((ch * 32 + 16 * h) ^ swz)));
                e = __builtin_amdgcn_mfma_f32_32x32x16_bf16(kf, qf[ch], e, 0, 0, 0);
            }
        }

        // ---- online softmax over the 32 keys of this tile (per query i=l31)
        float a01 = fmaxf(e[0], e[1]),   a23 = fmaxf(e[2], e[3]);
        float a45 = fmaxf(e[4], e[5]),   a67 = fmaxf(e[6], e[7]);
        float a89 = fmaxf(e[8], e[9]),   aAB = fmaxf(e[10], e[11]);
        float aCD = fmaxf(e[12], e[13]), aEF = fmaxf(e[14], e[15]);
        float mt = fmaxf(fmaxf(fmaxf(a01, a23), fmaxf(a45, a67)),
                         fmaxf(fmaxf(a89, aAB), fmaxf(aCD, aEF)));
        mt = fmaxf(mt, __shfl_xor(mt, 32, 64));
        const float mn = fmaxf(m_run, mt);
        const float sc = __expf(m_run - mn);
        float rs = 0.0f;
        #pragma unroll
        for (int rr = 0; rr < 16; ++rr) { float pv = __expf(e[rr] - mn); e[rr] = pv; rs += pv; }
        rs += __shfl_xor(rs, 32, 64);
        l_run = l_run * sc + rs;
        m_run = mn;
        #pragma unroll
        for (int cb = 0; cb < 4; ++cb)
            #pragma unroll
            for (int rr = 0; rr < 16; ++rr) accO[cb][rr] *= sc;

        // pack P: B-frag element e of chunk jc = p_reg[8*jc+e]
        i32x4 p0, p1;
        p0[0] = pk2(e[0], e[1]);   p0[1] = pk2(e[2], e[3]);
        p0[2] = pk2(e[4], e[5]);   p0[3] = pk2(e[6], e[7]);
        p1[0] = pk2(e[8], e[9]);   p1[1] = pk2(e[10], e[11]);
        p1[2] = pk2(e[12], e[13]); p1[3] = pk2(e[14], e[15]);
        const bf16x8 pf0 = __builtin_bit_cast(bf16x8, p0);
        const bf16x8 pf1 = __builtin_bit_cast(bf16x8, p1);

        // ---- accO[c][i] += sum_j V[c,j] P[j,i]
        #pragma unroll
        for (int cb = 0; cb < 4; ++cb) {
            const char* vrow = vbuf + (cb * 32 + l31) * 64;
            const int   vsw  = (l31 & 7) << 3;
            i32x2 a0 = *(const i32x2*)(vrow + ((8 * h)      ^ vsw));
            i32x2 a1 = *(const i32x2*)(vrow + ((16 + 8 * h) ^ vsw));
            i32x4 vv; vv[0] = a0[0]; vv[1] = a0[1]; vv[2] = a1[0]; vv[3] = a1[1];
            accO[cb] = __builtin_amdgcn_mfma_f32_32x32x16_bf16(
                __builtin_bit_cast(bf16x8, vv), pf0, accO[cb], 0, 0, 0);
            i32x2 b0 = *(const i32x2*)(vrow + ((32 + 8 * h) ^ vsw));
            i32x2 b1 = *(const i32x2*)(vrow + ((48 + 8 * h) ^ vsw));
            i32x4 vv1; vv1[0] = b0[0]; vv1[1] = b0[1]; vv1[2] = b1[0]; vv1[3] = b1[1];
            accO[cb] = __builtin_amdgcn_mfma_f32_32x32x16_bf16(
                __builtin_bit_cast(bf16x8, vv1), pf1, accO[cb], 0, 0, 0);
        }

        __syncthreads();                       // everyone done reading tile t
        if (t + 1 < 32) write_tile();          // overwrite buffer with t+1
    }

    // ---- combine the 4 key-splits per q-block, divide, add residual ----
    float* comb = (float*)smem;                // [8][1024] : [qb*4+s][c_loc*32+i]
    float* ml   = (float*)(smem + 32768);      // [8][64]   : m then l
    if (h == 0) {
        ml[(qb * 4 + s) * 64 + l31]      = m_run;
        ml[(qb * 4 + s) * 64 + 32 + l31] = l_run;
    }
    __syncthreads();
    float wgt[4];
    {
        float ms[4], ls[4];
        #pragma unroll
        for (int s2 = 0; s2 < 4; ++s2) {
            ms[s2] = ml[(qb * 4 + s2) * 64 + l31];
            ls[s2] = ml[(qb * 4 + s2) * 64 + 32 + l31];
        }
        float M = fmaxf(fmaxf(ms[0], ms[1]), fmaxf(ms[2], ms[3]));
        float L = 0.0f;
        #pragma unroll
        for (int s2 = 0; s2 < 4; ++s2) { wgt[s2] = __expf(ms[s2] - M); L += ls[s2] * wgt[s2]; }
        const float invL = 1.0f / L;
        #pragma unroll
        for (int s2 = 0; s2 < 4; ++s2) wgt[s2] *= invL;
    }
    #pragma unroll
    for (int cb = 0; cb < 4; ++cb) {
        __syncthreads();
        #pragma unroll
        for (int rr = 0; rr < 16; ++rr)
            comb[(qb * 4 + s) * 1024 + ((rr & 3) + 8 * (rr >> 2) + 4 * h) * 32 + l31] = accO[cb][rr];
        __syncthreads();
        #pragma unroll
        for (int r2 = 0; r2 < 4; ++r2) {
            const int cl = 8 * s + 2 * r2 + h;
            float v = 0.0f;
            #pragma unroll
            for (int s2 = 0; s2 < 4; ++s2)
                v += wgt[s2] * comb[(qb * 4 + s2) * 1024 + cl * 32 + l31];
            const int cg = cb * 32 + cl;
            const size_t idx = (size_t)(b * C_ + cg) * N_ + i0 + l31;
            out[idx] = x[idx] + v;
        }
    }
}

extern "C" void kernel_launch(void* const* d_in, const int* in_sizes, int n_in,
                              void* d_out, int out_size, void* d_ws, size_t ws_size,
                              hipStream_t stream)
{
    const float* x  = (const float*)d_in[0];
    const float* Wq = (const float*)d_in[1];
    const float* bq = (const float*)d_in[2];
    const float* Wk = (const float*)d_in[3];
    const float* bk = (const float*)d_in[4];
    const float* Wv = (const float*)d_in[5];
    const float* bv = (const float*)d_in[6];
    float* out = (float*)d_out;

    unsigned short* qT = (unsigned short*)d_ws;              // [B][N][C] bf16
    unsigned short* kT = qT + (size_t)B_ * N_ * C_;          // [B][N][C] bf16
    unsigned short* vM = kT + (size_t)B_ * N_ * C_;          // [B][C][N] bf16

    proj_kernel<<<384, 256, 0, stream>>>(x, Wq, bq, Wk, bk, Wv, bv, qT, kT, vM);
    attn_kernel<<<256, 512, 0, stream>>>(x, qT, kT, vM, out);
}

// Round 2
// 104.882 us; speedup vs baseline: 1.1625x; 1.1625x over previous
//
#include <hip/hip_runtime.h>

#define B_ 4
#define C_ 128
#define N_ 4096
#define LOG2E 1.44269504088896340736f

typedef __bf16 bf16x8 __attribute__((ext_vector_type(8)));
typedef float  f32x16 __attribute__((ext_vector_type(16)));
typedef int    i32x4  __attribute__((ext_vector_type(4)));
typedef int    i32x2  __attribute__((ext_vector_type(2)));

static __device__ __forceinline__ unsigned int bfbits(float f) {
    unsigned int u = __float_as_uint(f);
    u += 0x7FFFu + ((u >> 16) & 1u);   // round-to-nearest-even
    return u >> 16;
}
static __device__ __forceinline__ int pk2(float lo, float hi) {
    return (int)(bfbits(lo) | (bfbits(hi) << 16));
}

// ---------------- projection: q/k/v = W @ x + b (1x1 conv) -------------
// qT,kT stored [B][N][C] bf16 (q scaled by log2e); v stored [B][C][N] bf16.
__global__ __launch_bounds__(256) void proj_kernel(
    const float* __restrict__ x,
    const float* __restrict__ Wq, const float* __restrict__ bq,
    const float* __restrict__ Wk, const float* __restrict__ bk,
    const float* __restrict__ Wv, const float* __restrict__ bv,
    unsigned short* __restrict__ qT, unsigned short* __restrict__ kTt,
    unsigned short* __restrict__ vMat)
{
    __shared__ __align__(16) char wlds[32768];   // W bf16, swizzled rows

    const int tid  = threadIdx.x;
    const int wave = tid >> 6;
    const int lane = tid & 63;
    const int col  = lane & 31;
    const int h    = lane >> 5;

    const int jw  = blockIdx.x * 4 + wave;   // 0..1535 = mat*512 + b*128 + nb
    const int mat = jw >> 9;                 // uniform per WG (bid>>7)
    const int rem = jw & 511;
    const int b   = rem >> 7;
    const int nb  = rem & 127;
    const int n   = nb * 32 + col;

    const float* W    = (mat == 0) ? Wq : (mat == 1) ? Wk : Wv;
    const float* bias = (mat == 0) ? bq : (mat == 1) ? bk : bv;
    const float  scale = (mat == 0) ? LOG2E : 1.0f;

    // cooperative W pack: fp32 -> bf16 (scaled), swizzled LDS rows (256B)
    #pragma unroll
    for (int k = 0; k < 16; ++k) {
        const int q = tid + k * 256;          // quad index, 4 floats each
        const int o = q >> 5;
        const int cb8 = (q & 31) * 8;         // byte offset of 4 bf16
        float4 w = *((const float4*)W + q);
        i32x2 d;
        d[0] = pk2(w.x * scale, w.y * scale);
        d[1] = pk2(w.z * scale, w.w * scale);
        *(i32x2*)(wlds + o * 256 + (cb8 ^ ((o & 7) << 4))) = d;
    }
    __syncthreads();

    // B-operand fragments of x: element e of group h <-> c = ch*16 + 8h + e
    bf16x8 xf[8];
    const float* xcol = x + (size_t)b * C_ * N_ + n;
    #pragma unroll
    for (int ch = 0; ch < 8; ++ch) {
        const int c0 = ch * 16 + 8 * h;
        i32x4 r;
        r[0] = pk2(xcol[(size_t)(c0 + 0) * N_], xcol[(size_t)(c0 + 1) * N_]);
        r[1] = pk2(xcol[(size_t)(c0 + 2) * N_], xcol[(size_t)(c0 + 3) * N_]);
        r[2] = pk2(xcol[(size_t)(c0 + 4) * N_], xcol[(size_t)(c0 + 5) * N_]);
        r[3] = pk2(xcol[(size_t)(c0 + 6) * N_], xcol[(size_t)(c0 + 7) * N_]);
        xf[ch] = __builtin_bit_cast(bf16x8, r);
    }

    f32x16 acc[4];
    #pragma unroll
    for (int ob = 0; ob < 4; ++ob)
        #pragma unroll
        for (int rr = 0; rr < 16; ++rr) acc[ob][rr] = 0.0f;

    const int swzw = (col & 7) << 4;
    #pragma unroll
    for (int ch = 0; ch < 8; ++ch) {
        #pragma unroll
        for (int ob = 0; ob < 4; ++ob) {
            const char* wrow = wlds + (ob * 32 + col) * 256;
            bf16x8 wf = __builtin_bit_cast(bf16x8,
                *(const i32x4*)(wrow + ((ch * 32 + 16 * h) ^ swzw)));
            acc[ob] = __builtin_amdgcn_mfma_f32_32x32x16_bf16(
                wf, xf[ch], acc[ob], 0, 0, 0);
        }
    }

    // D[o][n]: lane col n = l&31, row o = ob*32 + (rr&3) + 8*(rr>>2) + 4h
    if (mat < 2) {
        unsigned short* dst = ((mat == 0) ? qT : kTt) + (size_t)(b * N_ + n) * C_;
        #pragma unroll
        for (int ob = 0; ob < 4; ++ob) {
            #pragma unroll
            for (int qd = 0; qd < 4; ++qd) {
                const int obase = ob * 32 + 8 * qd + 4 * h;
                const float f0 = acc[ob][4 * qd + 0] + bias[obase + 0] * scale;
                const float f1 = acc[ob][4 * qd + 1] + bias[obase + 1] * scale;
                const float f2 = acc[ob][4 * qd + 2] + bias[obase + 2] * scale;
                const float f3 = acc[ob][4 * qd + 3] + bias[obase + 3] * scale;
                i32x2 st; st[0] = pk2(f0, f1); st[1] = pk2(f2, f3);
                *(i32x2*)(dst + obase) = st;
            }
        }
    } else {
        unsigned short* dst = vMat + (size_t)b * C_ * N_ + n;
        #pragma unroll
        for (int ob = 0; ob < 4; ++ob) {
            #pragma unroll
            for (int rr = 0; rr < 16; ++rr) {
                const int o = ob * 32 + (rr & 3) + 8 * (rr >> 2) + 4 * h;
                dst[(size_t)o * N_] = (unsigned short)bfbits(acc[ob][rr] + bias[o]);
            }
        }
    }
}

// ---------------- flash attention + residual ---------------------------
// 256 WGs x 512 thr. 8 waves = 2 q-blocks(32) x 4 key-splits(1024 keys).
// Double-buffered K/V tiles (32 keys), ONE barrier per tile.
__global__ __launch_bounds__(512, 2) void attn_kernel(
    const float* __restrict__ x,
    const unsigned short* __restrict__ qT,
    const unsigned short* __restrict__ kTt,
    const unsigned short* __restrict__ vMat,
    float* __restrict__ out)
{
    __shared__ __align__(16) char smem[131072];

    const int tid  = threadIdx.x;
    const int wave = tid >> 6;
    const int lane = tid & 63;
    const int l31  = lane & 31;
    const int h    = lane >> 5;
    const int s    = wave >> 1;        // key split 0..3
    const int qb   = wave & 1;         // q block within WG

    const int Wg = blockIdx.x;
    const int b  = (Wg & 7) >> 1;                  // XCD-friendly mapping
    const int qg = (Wg >> 3) * 2 + (Wg & 1);       // 0..63
    const int i0 = qg * 64 + qb * 32;

    char* base = smem + s * 32768;     // [buf p: K 8KB | V 8KB] x2

    // Q fragments: element e of chunk ch <-> c = ch*16 + 8h + e
    bf16x8 qf[8];
    {
        const unsigned short* qrow = qT + (size_t)(b * N_ + i0 + l31) * C_;
        #pragma unroll
        for (int ch = 0; ch < 8; ++ch)
            qf[ch] = __builtin_bit_cast(bf16x8, *(const i32x4*)(qrow + ch * 16 + 8 * h));
    }

    f32x16 accO[4];
    #pragma unroll
    for (int cb = 0; cb < 4; ++cb)
        #pragma unroll
        for (int rr = 0; rr < 16; ++rr) accO[cb][rr] = 0.0f;
    float m_run = -1e30f, l_run = 0.0f;

    // staging: 128 threads per split stage kT(8KB)+v(8KB) per tile
    const int ts  = tid & 127;
    const int jr  = ts >> 2;
    const int seg = ts & 3;
    const int j0  = s * 1024;
    const char* kg = (const char*)kTt + (size_t)(b * N_) * C_ * 2;
    const char* vg = (const char*)vMat + (size_t)(b * C_ + ts) * N_ * 2;

    i32x4 kst[4], vst[4];
    auto load_tile = [&](int t) {
        const size_t krow = (size_t)(j0 + t * 32 + jr) * 256;
        const size_t vcol = (size_t)(j0 + t * 32) * 2;
        #pragma unroll
        for (int u = 0; u < 4; ++u) {
            kst[u] = *(const i32x4*)(kg + krow + seg * 64 + u * 16);
            vst[u] = *(const i32x4*)(vg + vcol + u * 16);
        }
    };
    // V row layout (64B): quad-swapped so PV A-frags are single b128:
    // bytes[0:16)=j{0-3,8-11} [16:32)=j{4-7,12-15} [32:48)=j{16-19,24-27} [48:64)=j{20-23,28-31}
    auto write_tile = [&](char* kb, char* vb) {
        #pragma unroll
        for (int u = 0; u < 4; ++u)
            *(i32x4*)(kb + jr * 256 + ((seg * 64 + u * 16) ^ ((jr & 7) << 4))) = kst[u];
        const int vsw = ((ts >> 1) & 3) << 4;
        char* vrow = vb + ts * 64;
        i32x4 w;
        w[0] = vst[0][0]; w[1] = vst[0][1]; w[2] = vst[1][0]; w[3] = vst[1][1];
        *(i32x4*)(vrow + (0 ^ vsw)) = w;
        w[0] = vst[0][2]; w[1] = vst[0][3]; w[2] = vst[1][2]; w[3] = vst[1][3];
        *(i32x4*)(vrow + (16 ^ vsw)) = w;
        w[0] = vst[2][0]; w[1] = vst[2][1]; w[2] = vst[3][0]; w[3] = vst[3][1];
        *(i32x4*)(vrow + (32 ^ vsw)) = w;
        w[0] = vst[2][2]; w[1] = vst[2][3]; w[2] = vst[3][2]; w[3] = vst[3][3];
        *(i32x4*)(vrow + (48 ^ vsw)) = w;
    };

    load_tile(0);
    write_tile(base, base + 8192);
    __syncthreads();

    #pragma unroll 1
    for (int t = 0; t < 32; ++t) {
        char* kb = base + (t & 1) * 16384;
        char* vb = kb + 8192;
        if (t + 1 < 32) load_tile(t + 1);     // issue early (T14)

        // E^T[j][i] = sum_c K[c,j] Q[c,i] : A=K^T frag (row j=l31), B=Q frag
        f32x16 ea, eb;
        #pragma unroll
        for (int rr = 0; rr < 16; ++rr) { ea[rr] = 0.0f; eb[rr] = 0.0f; }
        {
            const char* krow = kb + l31 * 256;
            const int   swz  = (l31 & 7) << 4;
            #pragma unroll
            for (int ch = 0; ch < 8; ch += 2) {
                bf16x8 k0 = __builtin_bit_cast(bf16x8,
                    *(const i32x4*)(krow + ((ch * 32 + 16 * h) ^ swz)));
                ea = __builtin_amdgcn_mfma_f32_32x32x16_bf16(k0, qf[ch], ea, 0, 0, 0);
                bf16x8 k1 = __builtin_bit_cast(bf16x8,
                    *(const i32x4*)(krow + (((ch + 1) * 32 + 16 * h) ^ swz)));
                eb = __builtin_amdgcn_mfma_f32_32x32x16_bf16(k1, qf[ch + 1], eb, 0, 0, 0);
            }
        }
        f32x16 e;
        #pragma unroll
        for (int rr = 0; rr < 16; ++rr) e[rr] = ea[rr] + eb[rr];

        // ---- online softmax (log2 domain; q pre-scaled by log2e) ----
        float a0 = fmaxf(fmaxf(e[0], e[1]), fmaxf(e[2], e[3]));
        float a1 = fmaxf(fmaxf(e[4], e[5]), fmaxf(e[6], e[7]));
        float a2 = fmaxf(fmaxf(e[8], e[9]), fmaxf(e[10], e[11]));
        float a3 = fmaxf(fmaxf(e[12], e[13]), fmaxf(e[14], e[15]));
        float mt = fmaxf(fmaxf(a0, a1), fmaxf(a2, a3));
        mt = fmaxf(mt, __shfl_xor(mt, 32, 64));
        if (!__all(mt <= m_run + 8.0f)) {      // defer-max (T13)
            const float mn = fmaxf(m_run, mt);
            const float sc = exp2f(m_run - mn);
            l_run *= sc;
            #pragma unroll
            for (int cb = 0; cb < 4; ++cb)
                #pragma unroll
                for (int rr = 0; rr < 16; ++rr) accO[cb][rr] *= sc;
            m_run = mn;
        }
        float rs = 0.0f;
        #pragma unroll
        for (int rr = 0; rr < 16; ++rr) {
            float pv = exp2f(e[rr] - m_run); e[rr] = pv; rs += pv;
        }
        rs += __shfl_xor(rs, 32, 64);
        l_run += rs;

        // pack P (consistent-k' map M2: k' = 8*(e>>2) + 4h + (e&3))
        i32x4 p0, p1;
        p0[0] = pk2(e[0], e[1]);   p0[1] = pk2(e[2], e[3]);
        p0[2] = pk2(e[4], e[5]);   p0[3] = pk2(e[6], e[7]);
        p1[0] = pk2(e[8], e[9]);   p1[1] = pk2(e[10], e[11]);
        p1[2] = pk2(e[12], e[13]); p1[3] = pk2(e[14], e[15]);
        const bf16x8 pf0 = __builtin_bit_cast(bf16x8, p0);
        const bf16x8 pf1 = __builtin_bit_cast(bf16x8, p1);

        // ---- accO[c][i] += sum_j V[c,j] P[j,i] : b128 V reads ----
        const int vsw2 = ((l31 >> 1) & 3) << 4;
        #pragma unroll
        for (int cb = 0; cb < 4; ++cb) {
            const char* vrow = vb + (cb * 32 + l31) * 64;
            bf16x8 v0 = __builtin_bit_cast(bf16x8,
                *(const i32x4*)(vrow + ((16 * h) ^ vsw2)));
            accO[cb] = __builtin_amdgcn_mfma_f32_32x32x16_bf16(v0, pf0, accO[cb], 0, 0, 0);
            bf16x8 v1 = __builtin_bit_cast(bf16x8,
                *(const i32x4*)(vrow + ((32 + 16 * h) ^ vsw2)));
            accO[cb] = __builtin_amdgcn_mfma_f32_32x32x16_bf16(v1, pf1, accO[cb], 0, 0, 0);
        }

        if (t + 1 < 32)
            write_tile(base + ((t + 1) & 1) * 16384,
                       base + ((t + 1) & 1) * 16384 + 8192);
        __syncthreads();                       // tile t+1 visible; t readers done
    }

    // ---- combine the 4 key-splits per q-block, divide, add residual ----
    float* comb = (float*)smem;                // [8][1024] : [qb*4+s][c_loc*32+i]
    float* ml   = (float*)(smem + 32768);      // [8][64]   : m then l
    if (h == 0) {
        ml[(qb * 4 + s) * 64 + l31]      = m_run;
        ml[(qb * 4 + s) * 64 + 32 + l31] = l_run;
    }
    __syncthreads();
    float wgt[4];
    {
        float ms[4], ls[4];
        #pragma unroll
        for (int s2 = 0; s2 < 4; ++s2) {
            ms[s2] = ml[(qb * 4 + s2) * 64 + l31];
            ls[s2] = ml[(qb * 4 + s2) * 64 + 32 + l31];
        }
        float M = fmaxf(fmaxf(ms[0], ms[1]), fmaxf(ms[2], ms[3]));
        float L = 0.0f;
        #pragma unroll
        for (int s2 = 0; s2 < 4; ++s2) { wgt[s2] = exp2f(ms[s2] - M); L += ls[s2] * wgt[s2]; }
        const float invL = 1.0f / L;
        #pragma unroll
        for (int s2 = 0; s2 < 4; ++s2) wgt[s2] *= invL;
    }
    #pragma unroll
    for (int cb = 0; cb < 4; ++cb) {
        __syncthreads();
        #pragma unroll
        for (int rr = 0; rr < 16; ++rr)
            comb[(qb * 4 + s) * 1024 + ((rr & 3) + 8 * (rr >> 2) + 4 * h) * 32 + l31] = accO[cb][rr];
        __syncthreads();
        #pragma unroll
        for (int r2 = 0; r2 < 4; ++r2) {
            const int cl = 8 * s + 2 * r2 + h;
            float v = 0.0f;
            #pragma unroll
            for (int s2 = 0; s2 < 4; ++s2)
                v += wgt[s2] * comb[(qb * 4 + s2) * 1024 + cl * 32 + l31];
            const int cg = cb * 32 + cl;
            const size_t idx = (size_t)(b * C_ + cg) * N_ + i0 + l31;
            out[idx] = x[idx] + v;
        }
    }
}

extern "C" void kernel_launch(void* const* d_in, const int* in_sizes, int n_in,
                              void* d_out, int out_size, void* d_ws, size_t ws_size,
                              hipStream_t stream)
{
    const float* x  = (const float*)d_in[0];
    const float* Wq = (const float*)d_in[1];
    const float* bq = (const float*)d_in[2];
    const float* Wk = (const float*)d_in[3];
    const float* bk = (const float*)d_in[4];
    const float* Wv = (const float*)d_in[5];
    const float* bv = (const float*)d_in[6];
    float* out = (float*)d_out;

    unsigned short* qT = (unsigned short*)d_ws;              // [B][N][C] bf16 (pre-scaled by log2e)
    unsigned short* kT = qT + (size_t)B_ * N_ * C_;          // [B][N][C] bf16
    unsigned short* vM = kT + (size_t)B_ * N_ * C_;          // [B][C][N] bf16

    proj_kernel<<<384, 256, 0, stream>>>(x, Wq, bq, Wk, bk, Wv, bv, qT, kT, vM);
    attn_kernel<<<256, 512, 0, stream>>>(x, qT, kT, vM, out);
}